// Round 5
// baseline (470.872 us; speedup 1.0000x reference)
//
#include <hip/hip_runtime.h>
#include <hip/hip_bf16.h>
#include <math.h>

// D=4096 K=512 HOP=512 WIN=16384 DX=25 B=128 K2=128 DY=128 K3=256 Y=193 M=128
// ws layout (bytes):
//   zxb  @ 0          : 128*25*512*2   = 3,276,800   (bf16 zx)
//   h2b  @ 3,276,800  : 128*256*193*2  = 12,644,352  (bf16 h2)
//   w1b  @ 15,921,152 : 32,768                      (bf16 w1 [k2][dy])
//   w2c  @ 15,953,920 : 1,638,400                   (bf16 w2 [k3][dx*128+k2])
//   bb   @ 17,592,320 : 128*49408*2    = 12,648,448 (bf16 beta)
//   xh   @ 30,240,768 : 128*16384*2    = 4,194,304  (fp16 x)       } dead after K1
//   fB   @ 34,435,072 : 4096*1024*2    = 8,388,608  (fp16 filt)    }
//   part @ 30,240,768 : 193*16384*4    = 12,648,448 (aliases xh/fB; used after K1)

typedef __attribute__((ext_vector_type(8))) short s8v;       // 8 bf16
typedef __attribute__((ext_vector_type(8))) _Float16 half8;  // 8 fp16
typedef __attribute__((ext_vector_type(16))) float f16v;     // 32x32 acc

__device__ inline ushort f2bf(float f) {
    union { float f; unsigned u; } v; v.f = f;
    unsigned u = v.u;
    return (ushort)((u + 0x7FFFu + ((u >> 16) & 1u)) >> 16);
}

// ---------------- K0x: x -> fp16 ----------------
__global__ void k0x_xh(const float* __restrict__ x, _Float16* __restrict__ xh) {
    int i = blockIdx.x * 256 + threadIdx.x;
    xh[i] = (_Float16)x[i];
}

// ---------------- K0f: filt (4096x1024) -> fp16 tiled [k/8][n][8] ----------------
__global__ __launch_bounds__(256)
void k0f_fB(const float* __restrict__ filt, _Float16* __restrict__ fB) {
    __shared__ float tile[8][257];
    const int t   = threadIdx.x;
    const int n0  = blockIdx.x * 256;
    const int kc8 = blockIdx.y;
    for (int idx = t; idx < 8 * 256; idx += 256) {
        int kk = idx >> 8, n = idx & 255;
        tile[kk][n] = filt[(kc8 * 8 + kk) * 1024 + n0 + n];
    }
    __syncthreads();
    half8 v;
#pragma unroll
    for (int j = 0; j < 8; j++) v[j] = (_Float16)tile[j][t];
    *(half8*)(fB + (size_t)kc8 * 8192 + (size_t)(n0 + t) * 8) = v;
}

// ---------------- K0a: w1 -> bf16 [k2][dy] ----------------
__global__ void k0a_w1b(const float* __restrict__ w1, ushort* __restrict__ w1b) {
    int i = blockIdx.x * 256 + threadIdx.x;
    w1b[i] = f2bf(w1[i]);
}

// ---------------- K0b: w2 (K3,K2,DX) -> bf16 [k3][dx*128+k2] ----------------
__global__ void k0b_w2c(const float* __restrict__ w2, ushort* __restrict__ w2c) {
    int i = blockIdx.x * 256 + threadIdx.x;   // 0..819199
    int k2 = i & 127;
    int dx = (i >> 7) % 25;
    int k3 = i / 3200;
    w2c[i] = f2bf(w2[(k3 * 128 + k2) * 25 + dx]);
}

// ---------------- K0c: beta -> bf16 ----------------
__global__ void k0c_bb(const float* __restrict__ beta, ushort* __restrict__ bb) {
    int i = blockIdx.x * 256 + threadIdx.x;
    bb[i] = f2bf(beta[i]);
}

// ---------------- K1: spec GEMM via fp16 MFMA + |.|^2 + log -> zxb ----------------
__global__ __launch_bounds__(256)
void k1_mfma(const _Float16* __restrict__ xh, const _Float16* __restrict__ fB,
             ushort* __restrict__ zxb) {
    __shared__ _Float16 Al[4096];
    const int t  = threadIdx.x;
    const int n0 = blockIdx.x * 128;
    const int m0 = blockIdx.y * 128;
    const int w  = t >> 6, l = t & 63;
    const int wm = (w >> 1) * 64, wn = (w & 1) * 64;
    const int qf = l >> 5;
    const int ml = l & 31;

    const int srow = t >> 1;
    const int sq   = t & 1;
    const int gm   = m0 + srow;
    const _Float16* apt = xh + (gm / 25) * 16384 + (gm % 25) * 512 + sq * 8;
    half8* Als8 = (half8*)Al;

    const _Float16* pB = fB + ((size_t)qf * 1024 + (size_t)(n0 + wn + ml)) * 8;

    f16v acc[2][2];
#pragma unroll
    for (int i = 0; i < 2; i++)
#pragma unroll
        for (int j = 0; j < 2; j++)
#pragma unroll
            for (int r = 0; r < 16; r++) acc[i][j][r] = 0.f;

    for (int kb = 0; kb < 128; kb++) {
        half8 v0 = *(const half8*)(apt + kb * 32);
        half8 v1 = *(const half8*)(apt + kb * 32 + 16);
        __syncthreads();
        Als8[t]       = v0;
        Als8[256 + t] = v1;
        __syncthreads();
#pragma unroll
        for (int s = 0; s < 2; s++) {
            half8 a0 = *(const half8*)((const char*)Al + s * 4096 + (wm + ml) * 32 + qf * 16);
            half8 a1 = *(const half8*)((const char*)Al + s * 4096 + (wm + 32 + ml) * 32 + qf * 16);
            const _Float16* pBk = pB + ((size_t)kb * 2 + s) * 16384;
            half8 b0 = *(const half8*)(pBk);
            half8 b1 = *(const half8*)(pBk + 256);
            acc[0][0] = __builtin_amdgcn_mfma_f32_32x32x16_f16(a0, b0, acc[0][0], 0, 0, 0);
            acc[0][1] = __builtin_amdgcn_mfma_f32_32x32x16_f16(a0, b1, acc[0][1], 0, 0, 0);
            acc[1][0] = __builtin_amdgcn_mfma_f32_32x32x16_f16(a1, b0, acc[1][0], 0, 0, 0);
            acc[1][1] = __builtin_amdgcn_mfma_f32_32x32x16_f16(a1, b1, acc[1][1], 0, 0, 0);
        }
    }

#pragma unroll
    for (int mt = 0; mt < 2; mt++)
#pragma unroll
        for (int nt = 0; nt < 2; nt++) {
#pragma unroll
            for (int r = 0; r < 16; r++) {
                float val = acc[mt][nt][r];
                float oth = __shfl_xor(val, 1, 64);
                if (!(l & 1)) {
                    float pw = fmaf(val, val, fmaf(oth, oth, 1e-14f));
                    int m = m0 + wm + mt * 32 + 4 * qf + (r & 3) + 8 * (r >> 2);
                    int n = n0 + wn + nt * 32 + ml;
                    zxb[m * 512 + (n >> 1)] = f2bf(logf(pw));
                }
            }
        }
}

// ---------------- K2 v3: fused conv1+conv2, barrier-light, zero zx-LDS ----------------
// grid (4 yt, 128 b), 512 threads = 8 waves: wave (u = k-quarter, h = y-half).
// conv1: wave computes k2 in [32u,32u+32) for its 32-y half, B-frags direct from global.
// h1 ping-pong in LDS (2 x 16 KB), ONE barrier per dx.
// conv2: wave accumulates k3 in [64u,64u+64) over full k2=128, its 32-y half.
__global__ __launch_bounds__(512, 4)
void k2_mfma(const ushort* __restrict__ zxb, const ushort* __restrict__ w1b,
             const ushort* __restrict__ w2c, ushort* __restrict__ h2b) {
    __shared__ ushort h1l[2 * 16 * 64 * 8];   // 32 KB ping-pong: [p][k2/8][y64][8]
    const int t  = threadIdx.x;
    const int yt = blockIdx.x;      // 0..3
    const int b  = blockIdx.y;
    const int y0 = yt * 64;
    const int wv = t >> 6;          // 0..7
    const int u  = wv & 3;          // k2/k3 unit
    const int h  = wv >> 2;         // y half
    const int l  = t & 63;
    const int yy = l & 31;
    const int q  = l >> 5;
    const int yh = 32 * h + yy;     // y within block tile (0..63)
    const int y  = y0 + yh;         // global y (0..255; >192 discarded)

    // persistent conv1 A-frags: k2-tile [32u, 32u+32)
    s8v w1f[8];
    {
        const ushort* wp = w1b + (32 * u + yy) * 128 + 8 * q;
#pragma unroll
        for (int ks = 0; ks < 8; ks++)
            w1f[ks] = *(const s8v*)(wp + 16 * ks);
    }

    // conv1 B-frag base: zxb[b][dx][2y + 16ks + 8q + j]  (dword-aligned)
    const ushort* zb = zxb + (size_t)b * 25 * 512 + 2 * y + 8 * q;
    // conv2 A-frag base: w2c[k3][dx*128 + k2], k3 = 64u + 32mt + yy
    const ushort* wa = w2c + (size_t)(64 * u + yy) * 3200 + 8 * q;

    f16v acc[2];
#pragma unroll
    for (int mt = 0; mt < 2; mt++)
#pragma unroll
        for (int r = 0; r < 16; r++) acc[mt][r] = 0.f;

    for (int dx = 0; dx < 25; dx++) {
        const int p = dx & 1;
        // ---- conv1: 8-step MFMA chain, B direct from global ----
        const ushort* zp = zb + dx * 512;
        f16v a1;
#pragma unroll
        for (int r = 0; r < 16; r++) a1[r] = 0.f;
#pragma unroll
        for (int ks = 0; ks < 8; ks++) {
            s8v bf = *(const s8v*)(zp + 16 * ks);
            a1 = __builtin_amdgcn_mfma_f32_32x32x16_bf16(w1f[ks], bf, a1, 0, 0, 0);
        }
        // relu + pack -> h1l[p]; k2 = 32u + 8g + 4q + i  -> chunk 4u+g, ushort off 4q
#pragma unroll
        for (int g = 0; g < 4; g++) {
            unsigned p0 = (unsigned)f2bf(fmaxf(a1[4 * g + 0], 0.f))
                        | ((unsigned)f2bf(fmaxf(a1[4 * g + 1], 0.f)) << 16);
            unsigned p1 = (unsigned)f2bf(fmaxf(a1[4 * g + 2], 0.f))
                        | ((unsigned)f2bf(fmaxf(a1[4 * g + 3], 0.f)) << 16);
            unsigned* dst = (unsigned*)(h1l + ((p * 16 + 4 * u + g) * 64 + yh) * 8 + 4 * q);
            dst[0] = p0; dst[1] = p1;
        }
        __syncthreads();
        // ---- conv2: full k2 contraction for k3-tile [64u, 64u+64) ----
        const ushort* ap = wa + dx * 128;
#pragma unroll
        for (int ks = 0; ks < 8; ks++) {
            s8v hb  = *(const s8v*)(h1l + ((p * 16 + 2 * ks + q) * 64 + yh) * 8);
            s8v a0  = *(const s8v*)(ap + 16 * ks);
            s8v a1f = *(const s8v*)(ap + (size_t)32 * 3200 + 16 * ks);
            acc[0] = __builtin_amdgcn_mfma_f32_32x32x16_bf16(a0, hb, acc[0], 0, 0, 0);
            acc[1] = __builtin_amdgcn_mfma_f32_32x32x16_bf16(a1f, hb, acc[1], 0, 0, 0);
        }
    }

    // ---- epilogue: store h2b (relu) ----
    if (y < 193) {
#pragma unroll
        for (int mt = 0; mt < 2; mt++) {
#pragma unroll
            for (int r = 0; r < 16; r++) {
                int k3 = 64 * u + 32 * mt + (r & 3) + 8 * (r >> 2) + 4 * q;
                h2b[((size_t)b * 256 + k3) * 193 + y] = f2bf(fmaxf(acc[mt][r], 0.f));
            }
        }
    }
}

// ---------------- K4: y partials via bf16 MFMA, 193-way k-split ----------------
__global__ __launch_bounds__(256)
void k4_mfma(const ushort* __restrict__ h2b, const ushort* __restrict__ bb,
             float* __restrict__ part) {
    const int t = threadIdx.x, w = t >> 6, l = t & 63;
    const int s = blockIdx.x;
    const int kb = s * 256;
    const int qf = l >> 5;
    const int ml = l & 31;
    const ushort* pa  = h2b + (size_t)(w * 32 + ml) * 49408 + kb + qf * 8;
    const ushort* pb0 = bb  + (size_t)ml * 49408 + kb + qf * 8;

    f16v acc[4];
#pragma unroll
    for (int nt = 0; nt < 4; nt++)
#pragma unroll
        for (int r = 0; r < 16; r++) acc[nt][r] = 0.f;

    for (int ks = 0; ks < 16; ks++) {
        s8v af = *(const s8v*)(pa + ks * 16);
#pragma unroll
        for (int nt = 0; nt < 4; nt++) {
            s8v bf = *(const s8v*)(pb0 + (size_t)nt * 32 * 49408 + ks * 16);
            acc[nt] = __builtin_amdgcn_mfma_f32_32x32x16_bf16(af, bf, acc[nt], 0, 0, 0);
        }
    }
    float* pp = part + (size_t)s * 16384;
#pragma unroll
    for (int nt = 0; nt < 4; nt++)
#pragma unroll
        for (int r = 0; r < 16; r++) {
            int m = w * 32 + 4 * qf + (r & 3) + 8 * (r >> 2);
            pp[m * 128 + nt * 32 + ml] = acc[nt][r];
        }
}

// ---------------- K5: reduce 193 partials ----------------
__global__ void k5_red(const float* __restrict__ part, float* __restrict__ out) {
    int i = blockIdx.x * 256 + threadIdx.x;
    float s = 0.f;
    for (int k = 0; k < 193; k++) s += part[(size_t)k * 16384 + i];
    out[i] = s;
}

extern "C" void kernel_launch(void* const* d_in, const int* in_sizes, int n_in,
                              void* d_out, int out_size, void* d_ws, size_t ws_size,
                              hipStream_t stream) {
    const float* x    = (const float*)d_in[0];
    const float* filt = (const float*)d_in[1];
    const float* w1   = (const float*)d_in[2];
    const float* w2   = (const float*)d_in[3];
    const float* beta = (const float*)d_in[4];
    float* out = (float*)d_out;

    char* ws = (char*)d_ws;
    ushort*   zxb  = (ushort*)(ws + 0);
    ushort*   h2b  = (ushort*)(ws + 3276800);
    ushort*   w1b  = (ushort*)(ws + 15921152);
    ushort*   w2c  = (ushort*)(ws + 15953920);
    ushort*   bb   = (ushort*)(ws + 17592320);
    _Float16* xh   = (_Float16*)(ws + 30240768);
    _Float16* fB   = (_Float16*)(ws + 34435072);
    float*    part = (float*)(ws + 30240768);

    k0x_xh<<<8192, 256, 0, stream>>>(x, xh);
    k0f_fB<<<dim3(4, 512), 256, 0, stream>>>(filt, fB);
    k0a_w1b<<<64, 256, 0, stream>>>(w1, w1b);
    k0b_w2c<<<3200, 256, 0, stream>>>(w2, w2c);
    k0c_bb<<<24704, 256, 0, stream>>>(beta, bb);
    k1_mfma<<<dim3(8, 25), 256, 0, stream>>>(xh, fB, zxb);
    k2_mfma<<<dim3(4, 128), 512, 0, stream>>>(zxb, w1b, w2c, h2b);
    k4_mfma<<<193, 256, 0, stream>>>(h2b, bb, part);
    k5_red<<<64, 256, 0, stream>>>(part, out);
}

// Round 6
// 382.283 us; speedup vs baseline: 1.2317x; 1.2317x over previous
//
#include <hip/hip_runtime.h>
#include <hip/hip_bf16.h>
#include <math.h>

// D=4096 K=512 HOP=512 WIN=16384 DX=25 B=128 K2=128 DY=128 K3=256 Y=193 M=128
// ws layout (bytes):
//   zxb  @ 0          : 128*25*512*2   = 3,276,800   (bf16 zx)
//   h2b  @ 3,276,800  : 128*256*193*2  = 12,644,352  (bf16 h2)
//   w1b  @ 15,921,152 : 32,768                      (bf16 w1 [k2][dy])
//   w2f  @ 15,953,920 : 1,638,400                   (bf16 w2 frag-tiled [dx][ks][q][k3][8])
//   bb   @ 17,592,320 : 128*49408*2    = 12,648,448 (bf16 beta)
//   xh   @ 30,240,768 : 128*16384*2    = 4,194,304  (fp16 x)       } dead after K1
//   fB   @ 34,435,072 : 4096*1024*2    = 8,388,608  (fp16 filt)    }
//   part @ 30,240,768 : 193*16384*4    = 12,648,448 (aliases xh/fB; used after K1)

typedef __attribute__((ext_vector_type(8))) short s8v;       // 8 bf16
typedef __attribute__((ext_vector_type(8))) _Float16 half8;  // 8 fp16
typedef __attribute__((ext_vector_type(16))) float f16v;     // 32x32 acc

__device__ inline ushort f2bf(float f) {
    union { float f; unsigned u; } v; v.f = f;
    unsigned u = v.u;
    return (ushort)((u + 0x7FFFu + ((u >> 16) & 1u)) >> 16);
}

// ---------------- K0x: x -> fp16 ----------------
__global__ void k0x_xh(const float* __restrict__ x, _Float16* __restrict__ xh) {
    int i = blockIdx.x * 256 + threadIdx.x;
    xh[i] = (_Float16)x[i];
}

// ---------------- K0f: filt (4096x1024) -> fp16 tiled [k/8][n][8] ----------------
__global__ __launch_bounds__(256)
void k0f_fB(const float* __restrict__ filt, _Float16* __restrict__ fB) {
    __shared__ float tile[8][257];
    const int t   = threadIdx.x;
    const int n0  = blockIdx.x * 256;
    const int kc8 = blockIdx.y;
    for (int idx = t; idx < 8 * 256; idx += 256) {
        int kk = idx >> 8, n = idx & 255;
        tile[kk][n] = filt[(kc8 * 8 + kk) * 1024 + n0 + n];
    }
    __syncthreads();
    half8 v;
#pragma unroll
    for (int j = 0; j < 8; j++) v[j] = (_Float16)tile[j][t];
    *(half8*)(fB + (size_t)kc8 * 8192 + (size_t)(n0 + t) * 8) = v;
}

// ---------------- K0a: w1 -> bf16 [k2][dy] ----------------
__global__ void k0a_w1b(const float* __restrict__ w1, ushort* __restrict__ w1b) {
    int i = blockIdx.x * 256 + threadIdx.x;
    w1b[i] = f2bf(w1[i]);
}

// ---------------- K0b: w2 (K3,K2,DX) -> bf16 frag-tiled [dx][ks][q][k3][j] ----------------
// k2 = 16*ks + 8*q + j ; conv2 A-frag for lane (yy,q) step ks is then 16B lane-consecutive.
__global__ void k0b_w2f(const float* __restrict__ w2, ushort* __restrict__ w2f) {
    int i = blockIdx.x * 256 + threadIdx.x;   // 0..819199
    int j  = i & 7;
    int k3 = (i >> 3) & 255;
    int q  = (i >> 11) & 1;
    int ks = (i >> 12) & 7;
    int dx = i >> 15;
    int k2 = 16 * ks + 8 * q + j;
    w2f[i] = f2bf(w2[(k3 * 128 + k2) * 25 + dx]);
}

// ---------------- K0c: beta -> bf16 ----------------
__global__ void k0c_bb(const float* __restrict__ beta, ushort* __restrict__ bb) {
    int i = blockIdx.x * 256 + threadIdx.x;
    bb[i] = f2bf(beta[i]);
}

// ---------------- K1: spec GEMM via fp16 MFMA + |.|^2 + log -> zxb ----------------
__global__ __launch_bounds__(256)
void k1_mfma(const _Float16* __restrict__ xh, const _Float16* __restrict__ fB,
             ushort* __restrict__ zxb) {
    __shared__ _Float16 Al[4096];
    const int t  = threadIdx.x;
    const int n0 = blockIdx.x * 128;
    const int m0 = blockIdx.y * 128;
    const int w  = t >> 6, l = t & 63;
    const int wm = (w >> 1) * 64, wn = (w & 1) * 64;
    const int qf = l >> 5;
    const int ml = l & 31;

    const int srow = t >> 1;
    const int sq   = t & 1;
    const int gm   = m0 + srow;
    const _Float16* apt = xh + (gm / 25) * 16384 + (gm % 25) * 512 + sq * 8;
    half8* Als8 = (half8*)Al;

    const _Float16* pB = fB + ((size_t)qf * 1024 + (size_t)(n0 + wn + ml)) * 8;

    f16v acc[2][2];
#pragma unroll
    for (int i = 0; i < 2; i++)
#pragma unroll
        for (int j = 0; j < 2; j++)
#pragma unroll
            for (int r = 0; r < 16; r++) acc[i][j][r] = 0.f;

    for (int kb = 0; kb < 128; kb++) {
        half8 v0 = *(const half8*)(apt + kb * 32);
        half8 v1 = *(const half8*)(apt + kb * 32 + 16);
        __syncthreads();
        Als8[t]       = v0;
        Als8[256 + t] = v1;
        __syncthreads();
#pragma unroll
        for (int s = 0; s < 2; s++) {
            half8 a0 = *(const half8*)((const char*)Al + s * 4096 + (wm + ml) * 32 + qf * 16);
            half8 a1 = *(const half8*)((const char*)Al + s * 4096 + (wm + 32 + ml) * 32 + qf * 16);
            const _Float16* pBk = pB + ((size_t)kb * 2 + s) * 16384;
            half8 b0 = *(const half8*)(pBk);
            half8 b1 = *(const half8*)(pBk + 256);
            acc[0][0] = __builtin_amdgcn_mfma_f32_32x32x16_f16(a0, b0, acc[0][0], 0, 0, 0);
            acc[0][1] = __builtin_amdgcn_mfma_f32_32x32x16_f16(a0, b1, acc[0][1], 0, 0, 0);
            acc[1][0] = __builtin_amdgcn_mfma_f32_32x32x16_f16(a1, b0, acc[1][0], 0, 0, 0);
            acc[1][1] = __builtin_amdgcn_mfma_f32_32x32x16_f16(a1, b1, acc[1][1], 0, 0, 0);
        }
    }

#pragma unroll
    for (int mt = 0; mt < 2; mt++)
#pragma unroll
        for (int nt = 0; nt < 2; nt++) {
#pragma unroll
            for (int r = 0; r < 16; r++) {
                float val = acc[mt][nt][r];
                float oth = __shfl_xor(val, 1, 64);
                if (!(l & 1)) {
                    float pw = fmaf(val, val, fmaf(oth, oth, 1e-14f));
                    int m = m0 + wm + mt * 32 + 4 * qf + (r & 3) + 8 * (r >> 2);
                    int n = n0 + wn + nt * 32 + ml;
                    zxb[m * 512 + (n >> 1)] = f2bf(logf(pw));
                }
            }
        }
}

// ---------------- K2 v4: fused conv1+conv2, y-tile 32, 4 blocks/CU ----------------
// grid (7 yt, 128 b), 256 threads = 4 waves (wave u = k-quarter).
// conv1: wave computes k2 [32u,32u+32) x 32 y; B-frags direct from global (prefetched).
// h1 ping-pong LDS (2 x 8 KB), ONE barrier per dx.
// conv2: wave accumulates k3 [64u,64u+64) over k2=128; A-frags lane-contiguous from w2f.
__global__ __launch_bounds__(256, 4)
void k2_mfma(const ushort* __restrict__ zxb, const ushort* __restrict__ w1b,
             const ushort* __restrict__ w2f, ushort* __restrict__ h2b) {
    __shared__ ushort h1l[2 * 16 * 32 * 8];   // 16 KB ping-pong: [p][k2/8][y32][8]
    const int t  = threadIdx.x;
    const int yt = blockIdx.x;      // 0..6
    const int b  = blockIdx.y;
    const int y0 = yt * 32;
    const int u  = t >> 6;          // wave 0..3
    const int l  = t & 63;
    const int yy = l & 31;
    const int q  = l >> 5;
    const int y  = y0 + yy;         // 0..223 (y>192 computed, discarded at store)

    // persistent conv1 A-frags: k2-tile [32u, 32u+32)
    s8v w1f[8];
    {
        const ushort* wp = w1b + (32 * u + yy) * 128 + 8 * q;
#pragma unroll
        for (int ks = 0; ks < 8; ks++)
            w1f[ks] = *(const s8v*)(wp + 16 * ks);
    }

    // conv1 B-frag base: zxb[b][dx][2y + 16ks + 8q + j]
    const ushort* zb = zxb + (size_t)b * 12800 + 2 * y + 8 * q;
    // conv2 A-frag base: w2f[((dx*8+ks)*2+q)*2048 + (64u+32mt+yy)*8 + j]
    const ushort* wa = w2f + (size_t)q * 2048 + (size_t)(64 * u + yy) * 8;

    f16v acc[2];
#pragma unroll
    for (int mt = 0; mt < 2; mt++)
#pragma unroll
        for (int r = 0; r < 16; r++) acc[mt][r] = 0.f;

    // prefetch conv1 B-frags for dx=0
    s8v bf[8];
#pragma unroll
    for (int ks = 0; ks < 8; ks++)
        bf[ks] = *(const s8v*)(zb + 16 * ks);

    for (int dx = 0; dx < 25; dx++) {
        const int p = dx & 1;
        // ---- conv1: 8-step MFMA chain on prefetched frags ----
        f16v a1;
#pragma unroll
        for (int r = 0; r < 16; r++) a1[r] = 0.f;
#pragma unroll
        for (int ks = 0; ks < 8; ks++)
            a1 = __builtin_amdgcn_mfma_f32_32x32x16_bf16(w1f[ks], bf[ks], a1, 0, 0, 0);
        // ---- prefetch B-frags for dx+1 (completes during conv1/write; drained at barrier) ----
        if (dx < 24) {
            const ushort* zp = zb + (dx + 1) * 512;
#pragma unroll
            for (int ks = 0; ks < 8; ks++)
                bf[ks] = *(const s8v*)(zp + 16 * ks);
        }
        // ---- relu + pack -> h1l[p]; k2 = 32u + 8g + 4q + i ----
#pragma unroll
        for (int g = 0; g < 4; g++) {
            unsigned p0 = (unsigned)f2bf(fmaxf(a1[4 * g + 0], 0.f))
                        | ((unsigned)f2bf(fmaxf(a1[4 * g + 1], 0.f)) << 16);
            unsigned p1 = (unsigned)f2bf(fmaxf(a1[4 * g + 2], 0.f))
                        | ((unsigned)f2bf(fmaxf(a1[4 * g + 3], 0.f)) << 16);
            unsigned* dst = (unsigned*)(h1l + ((p * 16 + 4 * u + g) * 32 + yy) * 8 + 4 * q);
            dst[0] = p0; dst[1] = p1;
        }
        __syncthreads();
        // ---- conv2: k3-tile [64u, 64u+64), full k2=128 ----
        const ushort* ap = wa + (size_t)dx * 32768;
#pragma unroll
        for (int ks = 0; ks < 8; ks++) {
            s8v hb  = *(const s8v*)(h1l + ((p * 16 + 2 * ks + q) * 32 + yy) * 8);
            s8v a0  = *(const s8v*)(ap + (size_t)ks * 4096);
            s8v a1f = *(const s8v*)(ap + (size_t)ks * 4096 + 256);
            acc[0] = __builtin_amdgcn_mfma_f32_32x32x16_bf16(a0, hb, acc[0], 0, 0, 0);
            acc[1] = __builtin_amdgcn_mfma_f32_32x32x16_bf16(a1f, hb, acc[1], 0, 0, 0);
        }
    }

    // ---- epilogue: store h2b (relu) ----
    if (y < 193) {
#pragma unroll
        for (int mt = 0; mt < 2; mt++) {
#pragma unroll
            for (int r = 0; r < 16; r++) {
                int k3 = 64 * u + 32 * mt + (r & 3) + 8 * (r >> 2) + 4 * q;
                h2b[((size_t)b * 256 + k3) * 193 + y] = f2bf(fmaxf(acc[mt][r], 0.f));
            }
        }
    }
}

// ---------------- K4: y partials via bf16 MFMA, 193-way k-split ----------------
__global__ __launch_bounds__(256)
void k4_mfma(const ushort* __restrict__ h2b, const ushort* __restrict__ bb,
             float* __restrict__ part) {
    const int t = threadIdx.x, w = t >> 6, l = t & 63;
    const int s = blockIdx.x;
    const int kb = s * 256;
    const int qf = l >> 5;
    const int ml = l & 31;
    const ushort* pa  = h2b + (size_t)(w * 32 + ml) * 49408 + kb + qf * 8;
    const ushort* pb0 = bb  + (size_t)ml * 49408 + kb + qf * 8;

    f16v acc[4];
#pragma unroll
    for (int nt = 0; nt < 4; nt++)
#pragma unroll
        for (int r = 0; r < 16; r++) acc[nt][r] = 0.f;

    for (int ks = 0; ks < 16; ks++) {
        s8v af = *(const s8v*)(pa + ks * 16);
#pragma unroll
        for (int nt = 0; nt < 4; nt++) {
            s8v bf = *(const s8v*)(pb0 + (size_t)nt * 32 * 49408 + ks * 16);
            acc[nt] = __builtin_amdgcn_mfma_f32_32x32x16_bf16(af, bf, acc[nt], 0, 0, 0);
        }
    }
    float* pp = part + (size_t)s * 16384;
#pragma unroll
    for (int nt = 0; nt < 4; nt++)
#pragma unroll
        for (int r = 0; r < 16; r++) {
            int m = w * 32 + 4 * qf + (r & 3) + 8 * (r >> 2);
            pp[m * 128 + nt * 32 + ml] = acc[nt][r];
        }
}

// ---------------- K5: reduce 193 partials ----------------
__global__ void k5_red(const float* __restrict__ part, float* __restrict__ out) {
    int i = blockIdx.x * 256 + threadIdx.x;
    float s = 0.f;
    for (int k = 0; k < 193; k++) s += part[(size_t)k * 16384 + i];
    out[i] = s;
}

extern "C" void kernel_launch(void* const* d_in, const int* in_sizes, int n_in,
                              void* d_out, int out_size, void* d_ws, size_t ws_size,
                              hipStream_t stream) {
    const float* x    = (const float*)d_in[0];
    const float* filt = (const float*)d_in[1];
    const float* w1   = (const float*)d_in[2];
    const float* w2   = (const float*)d_in[3];
    const float* beta = (const float*)d_in[4];
    float* out = (float*)d_out;

    char* ws = (char*)d_ws;
    ushort*   zxb  = (ushort*)(ws + 0);
    ushort*   h2b  = (ushort*)(ws + 3276800);
    ushort*   w1b  = (ushort*)(ws + 15921152);
    ushort*   w2f  = (ushort*)(ws + 15953920);
    ushort*   bb   = (ushort*)(ws + 17592320);
    _Float16* xh   = (_Float16*)(ws + 30240768);
    _Float16* fB   = (_Float16*)(ws + 34435072);
    float*    part = (float*)(ws + 30240768);

    k0x_xh<<<8192, 256, 0, stream>>>(x, xh);
    k0f_fB<<<dim3(4, 512), 256, 0, stream>>>(filt, fB);
    k0a_w1b<<<64, 256, 0, stream>>>(w1, w1b);
    k0b_w2f<<<3200, 256, 0, stream>>>(w2, w2f);
    k0c_bb<<<24704, 256, 0, stream>>>(beta, bb);
    k1_mfma<<<dim3(8, 25), 256, 0, stream>>>(xh, fB, zxb);
    k2_mfma<<<dim3(7, 128), 256, 0, stream>>>(zxb, w1b, w2f, h2b);
    k4_mfma<<<193, 256, 0, stream>>>(h2b, bb, part);
    k5_red<<<64, 256, 0, stream>>>(part, out);
}